// Round 1
// baseline (243.931 us; speedup 1.0000x reference)
//
#include <hip/hip_runtime.h>

// Sort_Latent_Layer: per row of (4096, 8192) fp32, view as 512 packets of 16,
// stable-argsort packets by first element, emit packets in sorted order.
//
// v2: enumeration (rank) sort replaces bitonic.
//  - 2 barriers total (was 45). Rank loop reads keys at wave-uniform LDS
//    addresses => broadcast, zero bank conflicts, zero syncs.
//  - Keys packed as sortable uint64: (monotonic(f32) << 16) | packet_idx.
//    Single u64 compare gives exact stable-argsort semantics (ties by idx;
//    -0.0 canonicalized to +0.0 so -0/+0 compare equal like the reference).
//  - LDS row stored XOR-swizzled (float4 index e ^= (e>>3)&7): staging writes
//    remain conflict-free, random-packet gather drops ~8-way -> ~2-way.
//  - Keys extracted in-register during staging (no stride-64B LDS read).
//  - NT=512: LDS 38.9KB -> 4 blocks/CU = 32 waves/CU (100% wave occupancy).

#define NPK 512       // packets per row
#define DIM 8192      // floats per row
#define NT  512       // threads per block

__device__ __forceinline__ int swz(int e) { return e ^ ((e >> 3) & 7); }

__global__ __launch_bounds__(NT, 8)
void sort_latent_kernel(const float* __restrict__ z, float* __restrict__ out) {
    __shared__ float4 row4[DIM / 4];                        // 32 KB, swizzled
    __shared__ __align__(16) unsigned long long keys[NPK];  // 4 KB
    __shared__ int srcs[NPK];                               // 2 KB

    const int t = threadIdx.x;
    const size_t rowoff = (size_t)blockIdx.x * DIM;
    const float4* __restrict__ zin4 = (const float4*)(z + rowoff);
    float4* __restrict__ out4 = (float4*)(out + rowoff);

    // ---- Stage row into LDS (swizzled) + build sortable keys in-register ----
#pragma unroll
    for (int i = 0; i < DIM / 4 / NT; ++i) {               // 4 iters
        const int e = t + NT * i;                          // float4 index
        const float4 v = zin4[e];                          // coalesced 16B/lane
        row4[swz(e)] = v;                                  // conflict-free write
        if ((t & 3) == 0) {                                // lane owns packet start
            const int p = (t >> 2) + (NT / 4) * i;         // packet index
            unsigned int u = __float_as_uint(v.x);
            if (u == 0x80000000u) u = 0u;                  // -0.0 -> +0.0 (tie)
            u = (u & 0x80000000u) ? ~u : (u | 0x80000000u);// monotonic map
            keys[p] = ((unsigned long long)u << 16) | (unsigned long long)p;
        }
    }
    __syncthreads();

    // ---- Enumeration sort: rank = #{j : K_j < K_i}. No barriers, broadcast
    // LDS reads (wave-uniform address). All K distinct => ranks a permutation.
    const unsigned long long k0 = keys[t];
    const ulonglong2* kv = (const ulonglong2*)keys;
    int r0 = 0;
#pragma unroll 8
    for (int j = 0; j < NPK / 2; j += 2) {
        const ulonglong2 a = kv[j];
        const ulonglong2 b = kv[j + 1];
        r0 += (int)(a.x < k0) + (int)(a.y < k0)
            + (int)(b.x < k0) + (int)(b.y < k0);
    }
    srcs[r0] = t;            // scatter: sorted position r0 holds packet t
    __syncthreads();

    // ---- Gather packets from swizzled LDS in sorted order; coalesced stores.
#pragma unroll
    for (int i = 0; i < DIM / 4 / NT; ++i) {               // 4 iters
        const int o = t + NT * i;                          // dest float4 slot
        const int src = srcs[o >> 2];                      // source packet
        out4[o] = row4[swz((src << 2) | (o & 3))];
    }
}

extern "C" void kernel_launch(void* const* d_in, const int* in_sizes, int n_in,
                              void* d_out, int out_size, void* d_ws, size_t ws_size,
                              hipStream_t stream) {
    const float* z = (const float*)d_in[0];
    float* out = (float*)d_out;
    const int nrows = in_sizes[0] / DIM;   // 4096
    sort_latent_kernel<<<nrows, NT, 0, stream>>>(z, out);
}

// Round 3
// 235.719 us; speedup vs baseline: 1.0348x; 1.0348x over previous
//
#include <hip/hip_runtime.h>

// Sort_Latent_Layer: per row of (4096, 8192) fp32, view as 512 packets of 16,
// stable-argsort packets by first element, emit packets in sorted order.
//
// v3 (resubmit — previous bench died to container infra, not the kernel):
// bitonic network, 1 element/thread, register-resident.
//  - 512 threads each hold one packed u64 (monotonic(f32)<<16 | idx) in a VGPR.
//  - 45 compare-exchange steps; the 39 with j<64 use __shfl_xor (in-wave,
//    no barrier, no LDS); only j=64/128/256 (6 steps) round-trip LDS.
//  - O(N log N) instructions (~420 wave-insts/wave) vs v2's O(N^2) rank loop
//    (~2600 wave-insts/wave) which was VALU-issue-bound at 62% VALUBusy.
//  - Staging + swizzled row buffer + swizzled gather unchanged from v2.

#define NPK 512       // packets per row
#define DIM 8192      // floats per row
#define NT  512       // threads per block

__device__ __forceinline__ int swz(int e) { return e ^ ((e >> 3) & 7); }

__device__ __forceinline__ unsigned long long shfl_xor_u64(unsigned long long v, int mask) {
    const int lo = __shfl_xor((int)(unsigned int)(v & 0xffffffffull), mask);
    const int hi = __shfl_xor((int)(unsigned int)(v >> 32), mask);
    return ((unsigned long long)(unsigned int)hi << 32) | (unsigned int)lo;
}

__global__ __launch_bounds__(NT, 8)
void sort_latent_kernel(const float* __restrict__ z, float* __restrict__ out) {
    __shared__ float4 row4[DIM / 4];                        // 32 KB, swizzled
    __shared__ __align__(16) unsigned long long keys[NPK];  // 4 KB (sort scratch)
    __shared__ int srcs[NPK];                               // 2 KB

    const int t = threadIdx.x;
    const size_t rowoff = (size_t)blockIdx.x * DIM;
    const float4* __restrict__ zin4 = (const float4*)(z + rowoff);
    float4* __restrict__ out4 = (float4*)(out + rowoff);

    // ---- Stage row into LDS (swizzled) + build sortable keys in-register ----
#pragma unroll
    for (int i = 0; i < DIM / 4 / NT; ++i) {               // 4 iters
        const int e = t + NT * i;                          // float4 index
        const float4 v = zin4[e];                          // coalesced 16B/lane
        row4[swz(e)] = v;                                  // conflict-free write
        if ((t & 3) == 0) {                                // lane owns packet start
            const int p = (t >> 2) + (NT / 4) * i;         // packet index
            unsigned int u = __float_as_uint(v.x);
            if (u == 0x80000000u) u = 0u;                  // -0.0 -> +0.0 (tie)
            u = (u & 0x80000000u) ? ~u : (u | 0x80000000u);// monotonic map
            keys[p] = ((unsigned long long)u << 16) | (unsigned long long)p;
        }
    }
    __syncthreads();

    // ---- Each thread owns one element; bitonic sort across 512 threads ----
    unsigned long long v = keys[t];

#pragma unroll
    for (int kk = 1; kk <= 9; ++kk) {                      // k = 2..512
        const int k = 1 << kk;
#pragma unroll
        for (int jj = kk - 1; jj >= 0; --jj) {             // j = k/2..1
            const int j = 1 << jj;
            unsigned long long vp;
            if (j < 64) {
                vp = shfl_xor_u64(v, j);                   // in-wave, no barrier
            } else {
                __syncthreads();                           // prior reads done
                keys[t] = v;
                __syncthreads();
                vp = keys[t ^ j];
            }
            // keep min if (ascending == lower-position), else keep max
            const bool take_min = (((t & k) == 0) == ((t & j) == 0));
            const bool lt = (v < vp);                      // never equal (idx unique)
            v = (take_min == lt) ? v : vp;
        }
    }

    // thread t now holds the element of sorted position t
    srcs[t] = (int)(v & 0xffffull);                        // source packet index
    __syncthreads();

    // ---- Gather packets from swizzled LDS in sorted order; coalesced stores.
#pragma unroll
    for (int i = 0; i < DIM / 4 / NT; ++i) {               // 4 iters
        const int o = t + NT * i;                          // dest float4 slot
        const int src = srcs[o >> 2];                      // source packet
        out4[o] = row4[swz((src << 2) | (o & 3))];
    }
}

extern "C" void kernel_launch(void* const* d_in, const int* in_sizes, int n_in,
                              void* d_out, int out_size, void* d_ws, size_t ws_size,
                              hipStream_t stream) {
    const float* z = (const float*)d_in[0];
    float* out = (float*)d_out;
    const int nrows = in_sizes[0] / DIM;   // 4096
    sort_latent_kernel<<<nrows, NT, 0, stream>>>(z, out);
}

// Round 6
// 232.115 us; speedup vs baseline: 1.0509x; 1.0155x over previous
//
#include <hip/hip_runtime.h>

// Sort_Latent_Layer: per row of (4096, 8192) fp32, view as 512 packets of 16,
// stable-argsort packets by first element, emit packets in sorted order.
//
// v4b: fix compile error — __builtin_nontemporal_store requires a clang
// ext_vector_type, not HIP's float4 class. Store via native vector alias.
//
// v4 design: no LDS row staging — gather straight from global (L2-hot).
//  - One packet = 16 floats = 64 B = one cache line. The per-thread key load
//    z[row, t*16] (stride 64 B) touches every line of the row, so the full row
//    is resident in the local XCD L2 before the gather needs it.
//  - Sort unchanged from v3: register-resident bitonic, 39/45 steps via
//    __shfl_xor, 6 steps via LDS u64 exchange (12 barriers).
//  - Gather: 4 lanes per packet read one 64 B segment (global_load_dwordx4,
//    L2 hit), stores fully coalesced + nontemporal (output never re-read;
//    keeps L2 retaining input rows — 32 CU x 4 blk x 32 KB = 4 MB = L2 size).
//  - LDS 38.9 KB -> 6.2 KB; removes 64 b128 LDS ops/block and all 3.7 M
//    gather bank conflicts.

#define NPK 512       // packets per row
#define DIM 8192      // floats per row
#define NT  512       // threads per block

typedef float vfloat4 __attribute__((ext_vector_type(4)));

__device__ __forceinline__ unsigned long long shfl_xor_u64(unsigned long long v, int mask) {
    const int lo = __shfl_xor((int)(unsigned int)(v & 0xffffffffull), mask);
    const int hi = __shfl_xor((int)(unsigned int)(v >> 32), mask);
    return ((unsigned long long)(unsigned int)hi << 32) | (unsigned int)lo;
}

__global__ __launch_bounds__(NT, 8)
void sort_latent_kernel(const float* __restrict__ z, float* __restrict__ out) {
    __shared__ __align__(16) unsigned long long keys[NPK];  // 4 KB (sort scratch)
    __shared__ int srcs[NPK];                               // 2 KB

    const int t = threadIdx.x;
    const size_t rowoff = (size_t)blockIdx.x * DIM;
    const float* __restrict__ zrow = z + rowoff;
    const vfloat4* __restrict__ zin4 = (const vfloat4*)zrow;
    vfloat4* __restrict__ out4 = (vfloat4*)(out + rowoff);

    // ---- Key load: one float per thread, one 64 B line per packet.
    // Doubles as the L2 prefetch of the entire row for the gather below.
    unsigned int u = __float_as_uint(zrow[t * 16]);
    if (u == 0x80000000u) u = 0u;                           // -0.0 -> +0.0 (tie)
    u = (u & 0x80000000u) ? ~u : (u | 0x80000000u);         // monotonic map
    unsigned long long v = ((unsigned long long)u << 16) | (unsigned long long)t;

    // ---- Bitonic sort across 512 threads, 1 element/thread ----
#pragma unroll
    for (int kk = 1; kk <= 9; ++kk) {                      // k = 2..512
        const int k = 1 << kk;
#pragma unroll
        for (int jj = kk - 1; jj >= 0; --jj) {             // j = k/2..1
            const int j = 1 << jj;
            unsigned long long vp;
            if (j < 64) {
                vp = shfl_xor_u64(v, j);                   // in-wave, no barrier
            } else {
                __syncthreads();                           // prior reads done
                keys[t] = v;
                __syncthreads();
                vp = keys[t ^ j];
            }
            const bool take_min = (((t & k) == 0) == ((t & j) == 0));
            const bool lt = (v < vp);                      // never equal (idx unique)
            v = (take_min == lt) ? v : vp;
        }
    }

    // thread t holds the element of sorted position t
    srcs[t] = (int)(v & 0xffffull);                        // source packet index
    __syncthreads();

    // ---- Gather packets straight from global (L2-hot); coalesced nt stores.
#pragma unroll
    for (int i = 0; i < DIM / 4 / NT; ++i) {               // 4 iters
        const int o = t + NT * i;                          // dest float4 slot
        const int src = srcs[o >> 2];                      // source packet
        const vfloat4 val = zin4[(src << 2) | (o & 3)];    // one 64B seg / packet
        __builtin_nontemporal_store(val, &out4[o]);
    }
}

extern "C" void kernel_launch(void* const* d_in, const int* in_sizes, int n_in,
                              void* d_out, int out_size, void* d_ws, size_t ws_size,
                              hipStream_t stream) {
    const float* z = (const float*)d_in[0];
    float* out = (float*)d_out;
    const int nrows = in_sizes[0] / DIM;   // 4096
    sort_latent_kernel<<<nrows, NT, 0, stream>>>(z, out);
}